// Round 1
// baseline (304.798 us; speedup 1.0000x reference)
//
#include <hip/hip_runtime.h>

// LocalityLoss: all four losses reduce to per-(t,h) and per-(t,w) sums of x and
// x^2 over the other axes (n_other = 512*56 = 28672 for both), followed by
// prefix/suffix cumsums of 56 values per image. Single memory-bound pass.

constexpr int T = 32, C = 512, H = 56, W = 56;
constexpr int HW = H * W;     // 3136
constexpr int PADW = 60;      // LDS row stride: 16B-aligned rows, breaks bank conflicts
constexpr int CPB = 8;        // channels per block
constexpr float EPS = 1e-6f;

__global__ __launch_bounds__(256) void sums_kernel(const float* __restrict__ x,
                                                   float* __restrict__ acc) {
    __shared__ float tile[H * PADW];  // 13440 B
    const int bid = blockIdx.x;
    const int t  = bid / (C / CPB);
    const int cg = bid % (C / CPB);
    const float* base = x + ((size_t)t * C + (size_t)cg * CPB) * HW;

    const int tid  = threadIdx.x;
    const int wave = tid >> 6;
    const int lane = tid & 63;

    float a0 = 0.f, a1 = 0.f;  // (sumsq, sum) — wave0: row lane; wave1: col lane

    for (int c = 0; c < CPB; ++c) {
        const float4* src = (const float4*)(base + c * HW);
        __syncthreads();  // tile no longer being read from previous channel
        // Stage 56x56 slice to LDS. 784 float4s; W==56 is a multiple of 4, so each
        // float4 lies within one row -> single aligned 16B LDS write.
        #pragma unroll
        for (int i = 0; i < 4; ++i) {
            int idx = tid + i * 256;
            if (idx < HW / 4) {
                float4 v = src[idx];
                int j = idx * 4;
                int h = j / 56;
                int w = j - h * 56;
                *(float4*)&tile[h * PADW + w] = v;
            }
        }
        __syncthreads();
        if (wave == 0 && lane < H) {
            // per-row (h) sums: 14 x ds_read_b128, effectively conflict-free at stride 60
            const float* rowp = &tile[lane * PADW];
            #pragma unroll
            for (int k = 0; k < W / 4; ++k) {
                float4 v = *(const float4*)&rowp[k * 4];
                a0 += v.x * v.x + v.y * v.y + v.z * v.z + v.w * v.w;
                a1 += v.x + v.y + v.z + v.w;
            }
        } else if (wave == 1 && lane < W) {
            // per-col (w) sums: consecutive lanes -> consecutive LDS addresses
            #pragma unroll 8
            for (int r = 0; r < H; ++r) {
                float v = tile[r * PADW + lane];
                a0 += v * v;
                a1 += v;
            }
        }
    }

    // acc layout: [0]=sq_h [1]=lin_h [2]=sq_w [3]=lin_w, each [T][56]
    if (wave == 0 && lane < H) {
        atomicAdd(&acc[(0 * T + t) * H + lane], a0);
        atomicAdd(&acc[(1 * T + t) * H + lane], a1);
    } else if (wave == 1 && lane < W) {
        atomicAdd(&acc[(2 * T + t) * W + lane], a0);
        atomicAdd(&acc[(3 * T + t) * W + lane], a1);
    }
}

__global__ void finalize_kernel(const float* __restrict__ acc, float* __restrict__ out) {
    const int tid = threadIdx.x;  // one wave; lanes 0..31 handle one t each
    float loss = 0.f;
    if (tid < T) {
        const float n_other = 28672.0f;  // 512*56 for both axes
        for (int pair = 0; pair < 2; ++pair) {
            const float* sq  = acc + (pair * 2 + 0) * T * 56 + tid * 56;
            const float* lin = acc + (pair * 2 + 1) * T * 56 + tid * 56;
            float psq = 0.f, plin = 0.f, ssq = 0.f, slin = 0.f;
            for (int i = 0; i < 56; ++i) {
                psq += sq[i];      plin += lin[i];
                ssq += sq[55 - i]; slin += lin[55 - i];
                float n = n_other * (float)(i + 1);
                loss += sqrtf(psq + 2.f * EPS * plin + EPS * EPS * n) + EPS;  // prefix [: i+1]
                loss += sqrtf(ssq + 2.f * EPS * slin + EPS * EPS * n) + EPS;  // suffix [55-i :]
            }
        }
    }
    #pragma unroll
    for (int off = 32; off > 0; off >>= 1) loss += __shfl_down(loss, off);
    if (tid == 0) out[0] = loss * (1.0f / 128.0f);  // /4 losses, /32 mean over t
}

extern "C" void kernel_launch(void* const* d_in, const int* in_sizes, int n_in,
                              void* d_out, int out_size, void* d_ws, size_t ws_size,
                              hipStream_t stream) {
    const float* x = (const float*)d_in[0];
    float* out = (float*)d_out;
    float* acc = (float*)d_ws;  // 4*32*56 floats = 28672 B

    hipMemsetAsync(acc, 0, 4 * T * 56 * sizeof(float), stream);
    sums_kernel<<<T * (C / CPB), 256, 0, stream>>>(x, acc);
    finalize_kernel<<<1, 64, 0, stream>>>(acc, out);
}

// Round 2
// 299.157 us; speedup vs baseline: 1.0189x; 1.0189x over previous
//
#include <hip/hip_runtime.h>

// LocalityLoss: all four losses reduce to per-(t,h) and per-(t,w) sums of x and
// x^2 over the other axes (n_other = 512*56 = 28672 for both), followed by
// prefix/suffix cumsums of 56 values per image. Single memory-bound pass.
//
// R2: 2 channels staged per iteration into 2 LDS tiles; all 4 waves reduce
// (wave0/1 -> tile0 rows/cols, wave2/3 -> tile1 rows/cols). Halves barrier
// count vs R1 and removes the 50% wave idling in the reduce phase.

constexpr int T = 32, C = 512, H = 56, W = 56;
constexpr int HW = H * W;     // 3136 floats per channel slice
constexpr int PADW = 60;      // LDS row stride: 16B-aligned rows, breaks pow2 conflicts
constexpr int CPB = 8;        // channels per block
constexpr float EPS = 1e-6f;

__global__ __launch_bounds__(256) void sums_kernel(const float* __restrict__ x,
                                                   float* __restrict__ acc) {
    __shared__ float tile[2][H * PADW];  // 2 x 13440 B = 26.9 KB -> 5 blocks/CU
    const int bid = blockIdx.x;
    const int t  = bid >> 6;   // C/CPB == 64 channel-groups
    const int cg = bid & 63;
    const float* base = x + ((size_t)t * C + (size_t)cg * CPB) * HW;

    const int tid  = threadIdx.x;
    const int wave = tid >> 6;
    const int lane = tid & 63;
    const int my_tile = wave >> 1;      // waves 0,1 -> tile0; waves 2,3 -> tile1
    const int role    = wave & 1;       // 0 = rows (h), 1 = cols (w)

    float a0 = 0.f, a1 = 0.f;           // (sumsq, sum)

    for (int it = 0; it < 4; ++it) {
        // channels 2*it and 2*it+1 are contiguous: one 1568-float4 stream
        const float4* src = (const float4*)(base + (size_t)(2 * it) * HW);
        __syncthreads();  // previous tiles fully consumed
        #pragma unroll
        for (int i = 0; i < 7; ++i) {
            int idx = tid + i * 256;
            if (idx < 2 * HW / 4) {     // 1568
                float4 v = src[idx];
                int tl = idx >= 784;
                int j  = idx - 784 * tl;     // float4 index within the slice
                int h  = j / 14;             // W/4 == 14 float4s per row
                int w  = (j - h * 14) * 4;
                *(float4*)&tile[tl][h * PADW + w] = v;
            }
        }
        __syncthreads();
        if (role == 0) {
            if (lane < H) {
                const float* rowp = &tile[my_tile][lane * PADW];
                #pragma unroll
                for (int k = 0; k < W / 4; ++k) {
                    float4 v = *(const float4*)&rowp[k * 4];
                    a0 += v.x * v.x + v.y * v.y + v.z * v.z + v.w * v.w;
                    a1 += v.x + v.y + v.z + v.w;
                }
            }
        } else {
            if (lane < W) {
                #pragma unroll 8
                for (int r = 0; r < H; ++r) {
                    float v = tile[my_tile][r * PADW + lane];
                    a0 += v * v;
                    a1 += v;
                }
            }
        }
    }

    // acc layout: [0]=sq_h [1]=lin_h [2]=sq_w [3]=lin_w, each [T][56]
    if (lane < 56) {
        if (role == 0) {
            atomicAdd(&acc[(0 * T + t) * 56 + lane], a0);
            atomicAdd(&acc[(1 * T + t) * 56 + lane], a1);
        } else {
            atomicAdd(&acc[(2 * T + t) * 56 + lane], a0);
            atomicAdd(&acc[(3 * T + t) * 56 + lane], a1);
        }
    }
}

__global__ void finalize_kernel(const float* __restrict__ acc, float* __restrict__ out) {
    const int tid = threadIdx.x;  // one wave; lanes 0..31 handle one t each
    float loss = 0.f;
    if (tid < T) {
        const float n_other = 28672.0f;  // 512*56 for both axes
        for (int pair = 0; pair < 2; ++pair) {
            const float* sq  = acc + (pair * 2 + 0) * T * 56 + tid * 56;
            const float* lin = acc + (pair * 2 + 1) * T * 56 + tid * 56;
            float psq = 0.f, plin = 0.f, ssq = 0.f, slin = 0.f;
            for (int i = 0; i < 56; ++i) {
                psq += sq[i];      plin += lin[i];
                ssq += sq[55 - i]; slin += lin[55 - i];
                float n = n_other * (float)(i + 1);
                loss += sqrtf(psq + 2.f * EPS * plin + EPS * EPS * n) + EPS;  // prefix [: i+1]
                loss += sqrtf(ssq + 2.f * EPS * slin + EPS * EPS * n) + EPS;  // suffix [55-i :]
            }
        }
    }
    #pragma unroll
    for (int off = 32; off > 0; off >>= 1) loss += __shfl_down(loss, off);
    if (tid == 0) out[0] = loss * (1.0f / 128.0f);  // /4 losses, /32 mean over t
}

extern "C" void kernel_launch(void* const* d_in, const int* in_sizes, int n_in,
                              void* d_out, int out_size, void* d_ws, size_t ws_size,
                              hipStream_t stream) {
    const float* x = (const float*)d_in[0];
    float* out = (float*)d_out;
    float* acc = (float*)d_ws;  // 4*32*56 floats = 28672 B

    hipMemsetAsync(acc, 0, 4 * T * 56 * sizeof(float), stream);
    sums_kernel<<<T * (C / CPB), 256, 0, stream>>>(x, acc);
    finalize_kernel<<<1, 64, 0, stream>>>(acc, out);
}